// Round 10
// baseline (327.936 us; speedup 1.0000x reference)
//
#include <hip/hip_runtime.h>
#include <hip/hip_fp16.h>
#include <hip/hip_cooperative_groups.h>

#define N_NODES 100000
#define N_EDGES 400000
#define BUILD_BLOCKS ((N_NODES + 255) / 256)   // 391

namespace cg = cooperative_groups;

// ---------- fused CSR build: zero + hist + scanA + scanBC + scatter ----------
__global__ __launch_bounds__(256) void build_kernel(const int* __restrict__ ei,
                                                    const float* __restrict__ ea,
                                                    int* __restrict__ deg,
                                                    int* __restrict__ rowptr,
                                                    int* __restrict__ cursor,
                                                    int* __restrict__ psum,
                                                    float4* __restrict__ edataA) {
    cg::grid_group grid = cg::this_grid();
    int tid = threadIdx.x, bid = blockIdx.x;
    int gtid = bid * 256 + tid;
    int gsz = gridDim.x * 256;                 // 100096

    // phase 0: zero deg
    for (int i = gtid; i < N_NODES; i += gsz) deg[i] = 0;
    grid.sync();

    // phase 1: histogram by dst
    for (int e = gtid; e < N_EDGES; e += gsz)
        atomicAdd(&deg[ei[N_EDGES + e]], 1);
    grid.sync();

    // phase 2: block-local exclusive scan (scanA)
    {
        __shared__ int sm[256];
        int i = gtid;
        int v = (i < N_NODES) ? deg[i] : 0;
        sm[tid] = v;
        __syncthreads();
        #pragma unroll
        for (int off = 1; off < 256; off <<= 1) {
            int t = (tid >= off) ? sm[tid - off] : 0;
            __syncthreads();
            sm[tid] += t;
            __syncthreads();
        }
        if (i < N_NODES) rowptr[i] = sm[tid] - v;
        if (tid == 255) psum[bid] = sm[255];
    }
    grid.sync();

    // phase 3: add block offsets (scanBC)
    {
        __shared__ int sm2[8];
        int acc = 0;
        for (int t = tid; t < bid; t += 256) acc += psum[t];
        #pragma unroll
        for (int off = 32; off; off >>= 1) acc += __shfl_down(acc, off, 64);
        if ((tid & 63) == 0) sm2[tid >> 6] = acc;
        __syncthreads();
        int base = sm2[0] + sm2[1] + sm2[2] + sm2[3];
        int i = gtid;
        if (i < N_NODES) {
            int r = rowptr[i] + base;
            rowptr[i] = r;
            cursor[i] = r;
        }
        if (i == 0) rowptr[N_NODES] = N_EDGES;
    }
    grid.sync();

    // phase 4: scatter payload {ea0,ea1,ea2,src} into dst-sorted slots
    for (int e = gtid; e < N_EDGES; e += gsz) {
        int s = ei[e], d = ei[N_EDGES + e];
        int pos = atomicAdd(&cursor[d], 1);
        edataA[pos] = make_float4(ea[e*3], ea[e*3+1], ea[e*3+2], __int_as_float(s));
    }
}

// ---------- conv1: aggregation + node update, x gathered directly ----------
__global__ __launch_bounds__(256) void conv1_kernel(const int* __restrict__ rowptr,
                                                    const float4* __restrict__ edataA,
                                                    const float* __restrict__ x,
                                                    const float* __restrict__ Wn1,
                                                    const float* __restrict__ bn1,
                                                    const float* __restrict__ root1,
                                                    const float* __restrict__ b1,
                                                    float* __restrict__ h1) {
    int gid = blockIdx.x * 256 + threadIdx.x;
    int n = gid >> 5, o = gid & 31;
    if (n >= N_NODES) return;
    float W[3][3], bb[3];
    #pragma unroll
    for (int d2 = 0; d2 < 3; ++d2)
        #pragma unroll
        for (int d = 0; d < 3; ++d) W[d2][d] = Wn1[d2*96 + d*32 + o];
    #pragma unroll
    for (int d = 0; d < 3; ++d) bb[d] = bn1[d*32 + o];

    int j0 = rowptr[n], j1 = rowptr[n + 1];
    float acc0 = 0.f, acc1 = 0.f;
    int j = j0;
    for (; j + 2 <= j1; j += 2) {
        float4 eA0 = edataA[j], eA1 = edataA[j+1];
        int s0 = __float_as_int(eA0.w), s1 = __float_as_int(eA1.w);
        float x00 = x[s0*3], x01 = x[s0*3+1], x02 = x[s0*3+2];
        float x10 = x[s1*3], x11 = x[s1*3+1], x12 = x[s1*3+2];
        float wd0 = fmaf(eA0.x, W[0][0], fmaf(eA0.y, W[1][0], fmaf(eA0.z, W[2][0], bb[0])));
        float wd1 = fmaf(eA0.x, W[0][1], fmaf(eA0.y, W[1][1], fmaf(eA0.z, W[2][1], bb[1])));
        float wd2 = fmaf(eA0.x, W[0][2], fmaf(eA0.y, W[1][2], fmaf(eA0.z, W[2][2], bb[2])));
        acc0 += fmaf(x00, wd0, fmaf(x01, wd1, x02 * wd2));
        float ud0 = fmaf(eA1.x, W[0][0], fmaf(eA1.y, W[1][0], fmaf(eA1.z, W[2][0], bb[0])));
        float ud1 = fmaf(eA1.x, W[0][1], fmaf(eA1.y, W[1][1], fmaf(eA1.z, W[2][1], bb[1])));
        float ud2 = fmaf(eA1.x, W[0][2], fmaf(eA1.y, W[1][2], fmaf(eA1.z, W[2][2], bb[2])));
        acc1 += fmaf(x10, ud0, fmaf(x11, ud1, x12 * ud2));
    }
    if (j < j1) {
        float4 eA0 = edataA[j];
        int s0 = __float_as_int(eA0.w);
        float x00 = x[s0*3], x01 = x[s0*3+1], x02 = x[s0*3+2];
        float wd0 = fmaf(eA0.x, W[0][0], fmaf(eA0.y, W[1][0], fmaf(eA0.z, W[2][0], bb[0])));
        float wd1 = fmaf(eA0.x, W[0][1], fmaf(eA0.y, W[1][1], fmaf(eA0.z, W[2][1], bb[1])));
        float wd2 = fmaf(eA0.x, W[0][2], fmaf(eA0.y, W[1][2], fmaf(eA0.z, W[2][2], bb[2])));
        acc0 += fmaf(x00, wd0, fmaf(x01, wd1, x02 * wd2));
    }
    float v = acc0 + acc1 + b1[o];
    v = fmaf(x[n*3],   root1[o],      v);
    v = fmaf(x[n*3+1], root1[32 + o], v);
    v = fmaf(x[n*3+2], root1[64 + o], v);
    h1[(size_t)n*32 + o] = fmaxf(v, 0.f);
}

// ---------- prep2: wave-per-node; h0 lanes: {g0,g1}, h1 lanes: {g2,g3,r2} ----------
// G2u[n*64 + 2o] = half2(g0,g1), G2u[n*64 + 2o+1] = half2(g2,g3), R2h[n*32+o] = r2
__global__ __launch_bounds__(256) void prep2_kernel(const float* __restrict__ h1,
                                                    const float* __restrict__ Wn2,
                                                    const float* __restrict__ bn2,
                                                    const float* __restrict__ root2,
                                                    unsigned int* __restrict__ G2u,
                                                    __half* __restrict__ R2h) {
    int lane = threadIdx.x & 63;
    int h = lane >> 5, o = lane & 31;
    // weight columns per half
    const float* q0 = (h == 0) ? (Wn2)        : (Wn2 + 2048);  // g0 | g2
    const float* q1 = (h == 0) ? (Wn2 + 1024) : (bn2);         // g1 | g3
    float w0[32], w1[32], w2[32];
    #pragma unroll
    for (int i = 0; i < 32; ++i) {
        w0[i] = q0[i*32 + o];
        w1[i] = q1[i*32 + o];
        w2[i] = root2[i*32 + o];          // only consumed by h==1
    }
    int w = (blockIdx.x * 256 + threadIdx.x) >> 6;
    int nwaves = (gridDim.x * 256) >> 6;
    for (int n = w; n < N_NODES; n += nwaves) {
        int nu = __builtin_amdgcn_readfirstlane(n);         // force scalar row addr
        const float4* hv = (const float4*)(h1 + (size_t)nu * 32);
        float a0 = 0.f, a1 = 0.f, a2 = 0.f;
        #pragma unroll
        for (int i4 = 0; i4 < 8; ++i4) {
            float4 t = hv[i4];                              // wave-uniform -> s_load
            a0 = fmaf(t.x, w0[i4*4+0], a0); a1 = fmaf(t.x, w1[i4*4+0], a1); a2 = fmaf(t.x, w2[i4*4+0], a2);
            a0 = fmaf(t.y, w0[i4*4+1], a0); a1 = fmaf(t.y, w1[i4*4+1], a1); a2 = fmaf(t.y, w2[i4*4+1], a2);
            a0 = fmaf(t.z, w0[i4*4+2], a0); a1 = fmaf(t.z, w1[i4*4+2], a1); a2 = fmaf(t.z, w2[i4*4+2], a2);
            a0 = fmaf(t.w, w0[i4*4+3], a0); a1 = fmaf(t.w, w1[i4*4+3], a1); a2 = fmaf(t.w, w2[i4*4+3], a2);
        }
        __half2 p = __floats2half2_rn(a0, a1);
        G2u[(size_t)nu*64 + o*2 + h] = *(const unsigned int*)&p;
        if (h) R2h[(size_t)nu*32 + o] = __float2half(a2);
    }
}

// ---------- conv2: PURE gather, fp16 G2 ----------
__global__ __launch_bounds__(256) void conv2_kernel(const int* __restrict__ rowptr,
                                                    const float4* __restrict__ edataA,
                                                    const uint2* __restrict__ G2h,
                                                    float* __restrict__ h2pre) {
    int gid = blockIdx.x * 256 + threadIdx.x;
    int n = gid >> 5, o = gid & 31;
    if (n >= N_NODES) return;
    int j0 = rowptr[n], j1 = rowptr[n + 1];
    float a0 = 0.f, a1 = 0.f;
    int j = j0;
    for (; j + 2 <= j1; j += 2) {
        float4 e0 = edataA[j], e1 = edataA[j+1];
        uint2 p0 = G2h[(size_t)__float_as_int(e0.w)*32 + o];
        uint2 p1 = G2h[(size_t)__float_as_int(e1.w)*32 + o];
        float2 f0a = __half22float2(*(const __half2*)&p0.x);
        float2 f0b = __half22float2(*(const __half2*)&p0.y);
        float2 f1a = __half22float2(*(const __half2*)&p1.x);
        float2 f1b = __half22float2(*(const __half2*)&p1.y);
        a0 += fmaf(e0.x, f0a.x, fmaf(e0.y, f0a.y, fmaf(e0.z, f0b.x, f0b.y)));
        a1 += fmaf(e1.x, f1a.x, fmaf(e1.y, f1a.y, fmaf(e1.z, f1b.x, f1b.y)));
    }
    if (j < j1) {
        float4 e0 = edataA[j];
        uint2 p0 = G2h[(size_t)__float_as_int(e0.w)*32 + o];
        float2 f0a = __half22float2(*(const __half2*)&p0.x);
        float2 f0b = __half22float2(*(const __half2*)&p0.y);
        a0 += fmaf(e0.x, f0a.x, fmaf(e0.y, f0a.y, fmaf(e0.z, f0b.x, f0b.y)));
    }
    h2pre[(size_t)n*32 + o] = a0 + a1;
}

// ---------- node2: + R2h + b2, ReLU, FC1 + FC2 (node-per-thread) ----------
__global__ __launch_bounds__(256) void node2_kernel(const float* __restrict__ h2pre,
                                                    const __half* __restrict__ R2h,
                                                    const float* __restrict__ b2,
                                                    const float* __restrict__ Wf1,
                                                    const float* __restrict__ bf1,
                                                    const float* __restrict__ Wf2,
                                                    const float* __restrict__ bf2,
                                                    float* __restrict__ out) {
    int n = blockIdx.x * 256 + threadIdx.x;
    if (n >= N_NODES) return;
    float h2[32];
    const float4* av = (const float4*)(h2pre + (size_t)n * 32);
    const uint2*  rv = (const uint2*)(R2h + (size_t)n * 32);
    #pragma unroll
    for (int j4 = 0; j4 < 8; ++j4) {
        float4 a = av[j4];
        uint2 rp = rv[j4 >> 1];
        unsigned int rw = (j4 & 1) ? rp.y : rp.x;
        float2 r2 = __half22float2(*(const __half2*)&rw);
        // j4 covers 4 floats but rp word covers only 2 halves; recompute properly:
        // R2h row: 32 halves = 8 uint2? No: 32*2B = 64B = uint2 x 8. Each uint2 = 4 halves.
        (void)rw; (void)r2;
        float4 rr;
        {
            float2 lo = __half22float2(*(const __half2*)&rp.x);
            float2 hi = __half22float2(*(const __half2*)&rp.y);
            if (j4 & 1) { rr = make_float4(hi.x, hi.y, 0.f, 0.f); }
            rr = make_float4(lo.x, lo.y, hi.x, hi.y);
        }
        // uint2 j4>>1 holds halves for j = (j4>>1)*4 .. +3 ; that's exactly j4 rounded pair.
        // Simpler correct mapping: halves for j4*4..j4*4+3 live in uint2 index j4/... 
        // 4 halves per uint2 -> uint2 index = j4*4/4 = j4. Fix:
        uint2 rp2 = rv[j4];
        float2 lo2 = __half22float2(*(const __half2*)&rp2.x);
        float2 hi2 = __half22float2(*(const __half2*)&rp2.y);
        rr = make_float4(lo2.x, lo2.y, hi2.x, hi2.y);
        #pragma unroll
        for (int k = 0; k < 4; ++k) {
            int j = j4*4 + k;
            float acc = (&a.x)[k] + b2[j] + (&rr.x)[k];
            h2[j] = fmaxf(acc, 0.f);
        }
    }
    float acc2 = bf2[0];
    #pragma unroll
    for (int j = 0; j < 32; ++j) {
        float a = bf1[j];
        #pragma unroll
        for (int i = 0; i < 32; ++i) a = fmaf(h2[i], Wf1[i*32 + j], a);
        acc2 = fmaf(fmaxf(a, 0.f), Wf2[j], acc2);
    }
    out[n] = acc2;
}

extern "C" void kernel_launch(void* const* d_in, const int* in_sizes, int n_in,
                              void* d_out, int out_size, void* d_ws, size_t ws_size,
                              hipStream_t stream) {
    const float* x     = (const float*)d_in[0];
    const int*   ei    = (const int*)  d_in[1];
    const float* ea    = (const float*)d_in[2];
    const float* Wn1   = (const float*)d_in[3];
    const float* bn1   = (const float*)d_in[4];
    const float* root1 = (const float*)d_in[5];
    const float* b1    = (const float*)d_in[6];
    const float* Wn2   = (const float*)d_in[7];
    const float* bn2   = (const float*)d_in[8];
    const float* root2 = (const float*)d_in[9];
    const float* b2    = (const float*)d_in[10];
    const float* Wf1   = (const float*)d_in[11];
    const float* bf1   = (const float*)d_in[12];
    const float* Wf2   = (const float*)d_in[13];
    const float* bf2   = (const float*)d_in[14];
    float* out = (float*)d_out;

    // workspace carve
    float*  h1     = (float*)d_ws;                          // [N,32] f32
    float*  h2pre  = h1 + (size_t)N_NODES*32;               // [N,32] f32
    unsigned int* G2u = (unsigned int*)(h2pre + (size_t)N_NODES*32); // [N,64] u32 (fp16x2)
    __half* R2h    = (__half*)(G2u + (size_t)N_NODES*64);   // [N,32] fp16
    float4* edataA = (float4*)(R2h + (size_t)N_NODES*32);   // [E]
    int*    deg    = (int*)(edataA + N_EDGES);              // [N]
    int*    rowptr = deg + N_NODES;                         // [N+1]
    int*    cursor = rowptr + N_NODES + 1;                  // [N]
    int*    psum   = cursor + N_NODES;                      // [BUILD_BLOCKS]

    int nb   = (N_NODES + 255) / 256;                       // 391
    int nb32 = (N_NODES * 32 + 255) / 256;                  // 12500

    {
        void* args[] = { (void*)&ei, (void*)&ea, (void*)&deg, (void*)&rowptr,
                         (void*)&cursor, (void*)&psum, (void*)&edataA };
        hipLaunchCooperativeKernel((const void*)build_kernel,
                                   dim3(BUILD_BLOCKS), dim3(256), args, 0, stream);
    }
    conv1_kernel<<<nb32, 256, 0, stream>>>(rowptr, edataA, x, Wn1, bn1, root1, b1, h1);
    prep2_kernel<<<1536, 256, 0, stream>>>(h1, Wn2, bn2, root2, G2u, R2h);
    conv2_kernel<<<nb32, 256, 0, stream>>>(rowptr, edataA, (const uint2*)G2u, h2pre);
    node2_kernel<<<nb, 256, 0, stream>>>(h2pre, R2h, b2, Wf1, bf1, Wf2, bf2, out);
}

// Round 11
// 151.269 us; speedup vs baseline: 2.1679x; 2.1679x over previous
//
#include <hip/hip_runtime.h>
#include <hip/hip_fp16.h>

#define N_NODES 100000
#define N_EDGES 400000
#define SCAN_BLOCKS ((N_NODES + 255) / 256)   // 391

// ---------- zero deg ----------
__global__ __launch_bounds__(256) void zero_kernel(int4* __restrict__ deg4) {
    int i = blockIdx.x * 256 + threadIdx.x;
    if (i < N_NODES / 4) deg4[i] = make_int4(0, 0, 0, 0);
}

// ---------- build CSR by dst: histogram ----------
__global__ __launch_bounds__(256) void hist_kernel(const int* __restrict__ ei,
                                                   int* __restrict__ deg) {
    int e = blockIdx.x * 256 + threadIdx.x;
    if (e < N_EDGES) atomicAdd(&deg[ei[N_EDGES + e]], 1);
}

// block-local exclusive scan of deg -> rowptr(local), block sums -> psum
__global__ __launch_bounds__(256) void scanA_kernel(const int* __restrict__ deg,
                                                    int* __restrict__ rowptr,
                                                    int* __restrict__ psum) {
    __shared__ int sm[256];
    int i = blockIdx.x * 256 + threadIdx.x;
    int v = (i < N_NODES) ? deg[i] : 0;
    sm[threadIdx.x] = v;
    __syncthreads();
    #pragma unroll
    for (int off = 1; off < 256; off <<= 1) {
        int t = (threadIdx.x >= off) ? sm[threadIdx.x - off] : 0;
        __syncthreads();
        sm[threadIdx.x] += t;
        __syncthreads();
    }
    if (i < N_NODES) rowptr[i] = sm[threadIdx.x] - v;
    if (threadIdx.x == 255) psum[blockIdx.x] = sm[255];
}

// merged scanB+scanC
__global__ __launch_bounds__(256) void scanBC_kernel(const int* __restrict__ psum,
                                                     int* __restrict__ rowptr,
                                                     int* __restrict__ cursor) {
    __shared__ int sm[8];
    int bid = blockIdx.x, tid = threadIdx.x;
    int acc = 0;
    for (int t = tid; t < bid; t += 256) acc += psum[t];
    #pragma unroll
    for (int off = 32; off; off >>= 1) acc += __shfl_down(acc, off, 64);
    if ((tid & 63) == 0) sm[tid >> 6] = acc;
    __syncthreads();
    int base = sm[0] + sm[1] + sm[2] + sm[3];
    int i = bid * 256 + tid;
    if (i < N_NODES) {
        int r = rowptr[i] + base;
        rowptr[i] = r;
        cursor[i] = r;
    }
    if (i == 0) rowptr[N_NODES] = N_EDGES;
}

// scatter edge payload {ea0,ea1,ea2,src} into dst-sorted slots (A only)
__global__ __launch_bounds__(256) void scatter_kernel(const int* __restrict__ ei,
                                                      const float* __restrict__ ea,
                                                      int* __restrict__ cursor,
                                                      float4* __restrict__ edataA) {
    int e = blockIdx.x * 256 + threadIdx.x;
    if (e >= N_EDGES) return;
    int s = ei[e], d = ei[N_EDGES + e];
    int pos = atomicAdd(&cursor[d], 1);
    edataA[pos] = make_float4(ea[e*3], ea[e*3+1], ea[e*3+2], __int_as_float(s));
}

// ---------- conv1: aggregation + node update, x gathered from L2 ----------
__global__ __launch_bounds__(256) void conv1_kernel(const int* __restrict__ rowptr,
                                                    const float4* __restrict__ edataA,
                                                    const float* __restrict__ x,
                                                    const float* __restrict__ Wn1,
                                                    const float* __restrict__ bn1,
                                                    const float* __restrict__ root1,
                                                    const float* __restrict__ b1,
                                                    float* __restrict__ h1) {
    int gid = blockIdx.x * 256 + threadIdx.x;
    int n = gid >> 5, o = gid & 31;
    if (n >= N_NODES) return;
    float W[3][3], bb[3];
    #pragma unroll
    for (int d2 = 0; d2 < 3; ++d2)
        #pragma unroll
        for (int d = 0; d < 3; ++d) W[d2][d] = Wn1[d2*96 + d*32 + o];
    #pragma unroll
    for (int d = 0; d < 3; ++d) bb[d] = bn1[d*32 + o];

    int j0 = rowptr[n], j1 = rowptr[n + 1];
    float acc0 = 0.f, acc1 = 0.f;
    int j = j0;
    for (; j + 2 <= j1; j += 2) {
        float4 eA0 = edataA[j], eA1 = edataA[j+1];
        int s0 = __float_as_int(eA0.w), s1 = __float_as_int(eA1.w);
        float x00 = x[s0*3], x01 = x[s0*3+1], x02 = x[s0*3+2];
        float x10 = x[s1*3], x11 = x[s1*3+1], x12 = x[s1*3+2];
        float wd0 = fmaf(eA0.x, W[0][0], fmaf(eA0.y, W[1][0], fmaf(eA0.z, W[2][0], bb[0])));
        float wd1 = fmaf(eA0.x, W[0][1], fmaf(eA0.y, W[1][1], fmaf(eA0.z, W[2][1], bb[1])));
        float wd2 = fmaf(eA0.x, W[0][2], fmaf(eA0.y, W[1][2], fmaf(eA0.z, W[2][2], bb[2])));
        acc0 += fmaf(x00, wd0, fmaf(x01, wd1, x02 * wd2));
        float ud0 = fmaf(eA1.x, W[0][0], fmaf(eA1.y, W[1][0], fmaf(eA1.z, W[2][0], bb[0])));
        float ud1 = fmaf(eA1.x, W[0][1], fmaf(eA1.y, W[1][1], fmaf(eA1.z, W[2][1], bb[1])));
        float ud2 = fmaf(eA1.x, W[0][2], fmaf(eA1.y, W[1][2], fmaf(eA1.z, W[2][2], bb[2])));
        acc1 += fmaf(x10, ud0, fmaf(x11, ud1, x12 * ud2));
    }
    if (j < j1) {
        float4 eA0 = edataA[j];
        int s0 = __float_as_int(eA0.w);
        float x00 = x[s0*3], x01 = x[s0*3+1], x02 = x[s0*3+2];
        float wd0 = fmaf(eA0.x, W[0][0], fmaf(eA0.y, W[1][0], fmaf(eA0.z, W[2][0], bb[0])));
        float wd1 = fmaf(eA0.x, W[0][1], fmaf(eA0.y, W[1][1], fmaf(eA0.z, W[2][1], bb[1])));
        float wd2 = fmaf(eA0.x, W[0][2], fmaf(eA0.y, W[1][2], fmaf(eA0.z, W[2][2], bb[2])));
        acc0 += fmaf(x00, wd0, fmaf(x01, wd1, x02 * wd2));
    }
    float v = acc0 + acc1 + b1[o];
    v = fmaf(x[n*3],   root1[o],      v);
    v = fmaf(x[n*3+1], root1[32 + o], v);
    v = fmaf(x[n*3+2], root1[64 + o], v);
    h1[(size_t)n*32 + o] = fmaxf(v, 0.f);
}

// ---------- prep2: wave-per-node; h0 lanes {g0,g1}, h1 lanes {g2,g3,r2} ----------
__global__ __launch_bounds__(256) void prep2_kernel(const float* __restrict__ h1,
                                                    const float* __restrict__ Wn2,
                                                    const float* __restrict__ bn2,
                                                    const float* __restrict__ root2,
                                                    unsigned int* __restrict__ G2u,
                                                    __half* __restrict__ R2h) {
    int lane = threadIdx.x & 63;
    int h = lane >> 5, o = lane & 31;
    const float* q0 = (h == 0) ? (Wn2)        : (Wn2 + 2048);  // g0 | g2
    const float* q1 = (h == 0) ? (Wn2 + 1024) : (bn2);         // g1 | g3
    float w0[32], w1[32], w2[32];
    #pragma unroll
    for (int i = 0; i < 32; ++i) {
        w0[i] = q0[i*32 + o];
        w1[i] = q1[i*32 + o];
        w2[i] = root2[i*32 + o];          // consumed by h==1 only
    }
    int w = (blockIdx.x * 256 + threadIdx.x) >> 6;
    int nwaves = (gridDim.x * 256) >> 6;
    for (int n = w; n < N_NODES; n += nwaves) {
        int nu = __builtin_amdgcn_readfirstlane(n);
        const float4* hv = (const float4*)(h1 + (size_t)nu * 32);
        float a0 = 0.f, a1 = 0.f, a2 = 0.f;
        #pragma unroll
        for (int i4 = 0; i4 < 8; ++i4) {
            float4 t = hv[i4];                          // wave-uniform -> s_load
            a0 = fmaf(t.x, w0[i4*4+0], a0); a1 = fmaf(t.x, w1[i4*4+0], a1); a2 = fmaf(t.x, w2[i4*4+0], a2);
            a0 = fmaf(t.y, w0[i4*4+1], a0); a1 = fmaf(t.y, w1[i4*4+1], a1); a2 = fmaf(t.y, w2[i4*4+1], a2);
            a0 = fmaf(t.z, w0[i4*4+2], a0); a1 = fmaf(t.z, w1[i4*4+2], a1); a2 = fmaf(t.z, w2[i4*4+2], a2);
            a0 = fmaf(t.w, w0[i4*4+3], a0); a1 = fmaf(t.w, w1[i4*4+3], a1); a2 = fmaf(t.w, w2[i4*4+3], a2);
        }
        __half2 p = __floats2half2_rn(a0, a1);
        G2u[(size_t)nu*64 + o*2 + h] = *(const unsigned int*)&p;
        if (h) R2h[(size_t)nu*32 + o] = __float2half(a2);
    }
}

// ---------- conv2: PURE gather, fp16 G2 ----------
__global__ __launch_bounds__(256) void conv2_kernel(const int* __restrict__ rowptr,
                                                    const float4* __restrict__ edataA,
                                                    const uint2* __restrict__ G2h,
                                                    float* __restrict__ h2pre) {
    int gid = blockIdx.x * 256 + threadIdx.x;
    int n = gid >> 5, o = gid & 31;
    if (n >= N_NODES) return;
    int j0 = rowptr[n], j1 = rowptr[n + 1];
    float a0 = 0.f, a1 = 0.f;
    int j = j0;
    for (; j + 2 <= j1; j += 2) {
        float4 e0 = edataA[j], e1 = edataA[j+1];
        uint2 p0 = G2h[(size_t)__float_as_int(e0.w)*32 + o];
        uint2 p1 = G2h[(size_t)__float_as_int(e1.w)*32 + o];
        float2 f0a = __half22float2(*(const __half2*)&p0.x);
        float2 f0b = __half22float2(*(const __half2*)&p0.y);
        float2 f1a = __half22float2(*(const __half2*)&p1.x);
        float2 f1b = __half22float2(*(const __half2*)&p1.y);
        a0 += fmaf(e0.x, f0a.x, fmaf(e0.y, f0a.y, fmaf(e0.z, f0b.x, f0b.y)));
        a1 += fmaf(e1.x, f1a.x, fmaf(e1.y, f1a.y, fmaf(e1.z, f1b.x, f1b.y)));
    }
    if (j < j1) {
        float4 e0 = edataA[j];
        uint2 p0 = G2h[(size_t)__float_as_int(e0.w)*32 + o];
        float2 f0a = __half22float2(*(const __half2*)&p0.x);
        float2 f0b = __half22float2(*(const __half2*)&p0.y);
        a0 += fmaf(e0.x, f0a.x, fmaf(e0.y, f0a.y, fmaf(e0.z, f0b.x, f0b.y)));
    }
    h2pre[(size_t)n*32 + o] = a0 + a1;
}

// ---------- node2: h2 = relu(h2pre + R2h + b2); FC1 + FC2 ----------
__global__ __launch_bounds__(256) void node2_kernel(const float* __restrict__ h2pre,
                                                    const __half* __restrict__ R2h,
                                                    const float* __restrict__ b2,
                                                    const float* __restrict__ Wf1,
                                                    const float* __restrict__ bf1,
                                                    const float* __restrict__ Wf2,
                                                    const float* __restrict__ bf2,
                                                    float* __restrict__ out) {
    int n = blockIdx.x * 256 + threadIdx.x;
    if (n >= N_NODES) return;
    float h2[32];
    const float4* av = (const float4*)(h2pre + (size_t)n * 32);
    const uint2*  rv = (const uint2*)(R2h + (size_t)n * 32);   // 8 x uint2, 4 halves each
    #pragma unroll
    for (int j4 = 0; j4 < 8; ++j4) {
        float4 a = av[j4];
        uint2 rp = rv[j4];
        float2 lo = __half22float2(*(const __half2*)&rp.x);
        float2 hi = __half22float2(*(const __half2*)&rp.y);
        float rr[4] = { lo.x, lo.y, hi.x, hi.y };
        #pragma unroll
        for (int k = 0; k < 4; ++k) {
            int j = j4*4 + k;
            h2[j] = fmaxf((&a.x)[k] + b2[j] + rr[k], 0.f);
        }
    }
    float acc2 = bf2[0];
    #pragma unroll
    for (int j = 0; j < 32; ++j) {
        float a = bf1[j];
        #pragma unroll
        for (int i = 0; i < 32; ++i) a = fmaf(h2[i], Wf1[i*32 + j], a);
        acc2 = fmaf(fmaxf(a, 0.f), Wf2[j], acc2);
    }
    out[n] = acc2;
}

extern "C" void kernel_launch(void* const* d_in, const int* in_sizes, int n_in,
                              void* d_out, int out_size, void* d_ws, size_t ws_size,
                              hipStream_t stream) {
    const float* x     = (const float*)d_in[0];
    const int*   ei    = (const int*)  d_in[1];
    const float* ea    = (const float*)d_in[2];
    const float* Wn1   = (const float*)d_in[3];
    const float* bn1   = (const float*)d_in[4];
    const float* root1 = (const float*)d_in[5];
    const float* b1    = (const float*)d_in[6];
    const float* Wn2   = (const float*)d_in[7];
    const float* bn2   = (const float*)d_in[8];
    const float* root2 = (const float*)d_in[9];
    const float* b2    = (const float*)d_in[10];
    const float* Wf1   = (const float*)d_in[11];
    const float* bf1   = (const float*)d_in[12];
    const float* Wf2   = (const float*)d_in[13];
    const float* bf2   = (const float*)d_in[14];
    float* out = (float*)d_out;

    // workspace carve
    float*  h1     = (float*)d_ws;                          // [N,32] f32
    float*  h2pre  = h1 + (size_t)N_NODES*32;               // [N,32] f32
    unsigned int* G2u = (unsigned int*)(h2pre + (size_t)N_NODES*32); // [N,64] u32 (fp16x2)
    __half* R2h    = (__half*)(G2u + (size_t)N_NODES*64);   // [N,32] fp16
    float4* edataA = (float4*)(R2h + (size_t)N_NODES*32);   // [E]
    int*    deg    = (int*)(edataA + N_EDGES);              // [N]
    int*    rowptr = deg + N_NODES;                         // [N+1]
    int*    cursor = rowptr + N_NODES + 1;                  // [N]
    int*    psum   = cursor + N_NODES;                      // [SCAN_BLOCKS]

    int eb   = (N_EDGES + 255) / 256;                       // 1563
    int nb   = (N_NODES + 255) / 256;                       // 391
    int nb32 = (N_NODES * 32 + 255) / 256;                  // 12500
    int zb   = (N_NODES / 4 + 255) / 256;                   // 98

    zero_kernel   <<<zb, 256, 0, stream>>>((int4*)deg);
    hist_kernel   <<<eb, 256, 0, stream>>>(ei, deg);
    scanA_kernel  <<<SCAN_BLOCKS, 256, 0, stream>>>(deg, rowptr, psum);
    scanBC_kernel <<<SCAN_BLOCKS, 256, 0, stream>>>(psum, rowptr, cursor);
    scatter_kernel<<<eb, 256, 0, stream>>>(ei, ea, cursor, edataA);
    conv1_kernel  <<<nb32, 256, 0, stream>>>(rowptr, edataA, x, Wn1, bn1, root1, b1, h1);
    prep2_kernel  <<<1536, 256, 0, stream>>>(h1, Wn2, bn2, root2, G2u, R2h);
    conv2_kernel  <<<nb32, 256, 0, stream>>>(rowptr, edataA, (const uint2*)G2u, h2pre);
    node2_kernel  <<<nb, 256, 0, stream>>>(h2pre, R2h, b2, Wf1, bf1, Wf2, bf2, out);
}

// Round 12
// 136.972 us; speedup vs baseline: 2.3942x; 1.1044x over previous
//
#include <hip/hip_runtime.h>
#include <hip/hip_fp16.h>

#define N_NODES 100000
#define N_EDGES 400000
#define SCAN_BLOCKS ((N_NODES + 255) / 256)   // 391

// ---------- zero deg ----------
__global__ __launch_bounds__(256) void zero_kernel(int4* __restrict__ deg4) {
    int i = blockIdx.x * 256 + threadIdx.x;
    if (i < N_NODES / 4) deg4[i] = make_int4(0, 0, 0, 0);
}

// ---------- hist by dst; atomic return value = rank of edge within its dst ----------
__global__ __launch_bounds__(256) void hist_kernel(const int* __restrict__ ei,
                                                   int* __restrict__ deg,
                                                   int* __restrict__ rank) {
    int e = blockIdx.x * 256 + threadIdx.x;
    if (e < N_EDGES) rank[e] = atomicAdd(&deg[ei[N_EDGES + e]], 1);
}

// block-local exclusive scan of deg -> rowptr(local), block sums -> psum
__global__ __launch_bounds__(256) void scanA_kernel(const int* __restrict__ deg,
                                                    int* __restrict__ rowptr,
                                                    int* __restrict__ psum) {
    __shared__ int sm[256];
    int i = blockIdx.x * 256 + threadIdx.x;
    int v = (i < N_NODES) ? deg[i] : 0;
    sm[threadIdx.x] = v;
    __syncthreads();
    #pragma unroll
    for (int off = 1; off < 256; off <<= 1) {
        int t = (threadIdx.x >= off) ? sm[threadIdx.x - off] : 0;
        __syncthreads();
        sm[threadIdx.x] += t;
        __syncthreads();
    }
    if (i < N_NODES) rowptr[i] = sm[threadIdx.x] - v;
    if (threadIdx.x == 255) psum[blockIdx.x] = sm[255];
}

// add block offsets (no cursor needed anymore)
__global__ __launch_bounds__(256) void scanBC_kernel(const int* __restrict__ psum,
                                                     int* __restrict__ rowptr) {
    __shared__ int sm[8];
    int bid = blockIdx.x, tid = threadIdx.x;
    int acc = 0;
    for (int t = tid; t < bid; t += 256) acc += psum[t];
    #pragma unroll
    for (int off = 32; off; off >>= 1) acc += __shfl_down(acc, off, 64);
    if ((tid & 63) == 0) sm[tid >> 6] = acc;
    __syncthreads();
    int base = sm[0] + sm[1] + sm[2] + sm[3];
    int i = bid * 256 + tid;
    if (i < N_NODES) rowptr[i] = rowptr[i] + base;
    if (i == 0) rowptr[N_NODES] = N_EDGES;
}

// scatter edge payload {ea0,ea1,ea2,src} — ATOMIC-FREE via rank
__global__ __launch_bounds__(256) void scatter_kernel(const int* __restrict__ ei,
                                                      const float* __restrict__ ea,
                                                      const int* __restrict__ rowptr,
                                                      const int* __restrict__ rank,
                                                      float4* __restrict__ edataA) {
    int e = blockIdx.x * 256 + threadIdx.x;
    if (e >= N_EDGES) return;
    int s = ei[e], d = ei[N_EDGES + e];
    int pos = rowptr[d] + rank[e];
    edataA[pos] = make_float4(ea[e*3], ea[e*3+1], ea[e*3+2], __int_as_float(s));
}

// ---------- conv1: aggregation + node update, x gathered from L2 ----------
__global__ __launch_bounds__(256) void conv1_kernel(const int* __restrict__ rowptr,
                                                    const float4* __restrict__ edataA,
                                                    const float* __restrict__ x,
                                                    const float* __restrict__ Wn1,
                                                    const float* __restrict__ bn1,
                                                    const float* __restrict__ root1,
                                                    const float* __restrict__ b1,
                                                    float* __restrict__ h1) {
    int gid = blockIdx.x * 256 + threadIdx.x;
    int n = gid >> 5, o = gid & 31;
    if (n >= N_NODES) return;
    float W[3][3], bb[3];
    #pragma unroll
    for (int d2 = 0; d2 < 3; ++d2)
        #pragma unroll
        for (int d = 0; d < 3; ++d) W[d2][d] = Wn1[d2*96 + d*32 + o];
    #pragma unroll
    for (int d = 0; d < 3; ++d) bb[d] = bn1[d*32 + o];

    int j0 = rowptr[n], j1 = rowptr[n + 1];
    float acc0 = 0.f, acc1 = 0.f;
    int j = j0;
    for (; j + 2 <= j1; j += 2) {
        float4 eA0 = edataA[j], eA1 = edataA[j+1];
        int s0 = __float_as_int(eA0.w), s1 = __float_as_int(eA1.w);
        float x00 = x[s0*3], x01 = x[s0*3+1], x02 = x[s0*3+2];
        float x10 = x[s1*3], x11 = x[s1*3+1], x12 = x[s1*3+2];
        float wd0 = fmaf(eA0.x, W[0][0], fmaf(eA0.y, W[1][0], fmaf(eA0.z, W[2][0], bb[0])));
        float wd1 = fmaf(eA0.x, W[0][1], fmaf(eA0.y, W[1][1], fmaf(eA0.z, W[2][1], bb[1])));
        float wd2 = fmaf(eA0.x, W[0][2], fmaf(eA0.y, W[1][2], fmaf(eA0.z, W[2][2], bb[2])));
        acc0 += fmaf(x00, wd0, fmaf(x01, wd1, x02 * wd2));
        float ud0 = fmaf(eA1.x, W[0][0], fmaf(eA1.y, W[1][0], fmaf(eA1.z, W[2][0], bb[0])));
        float ud1 = fmaf(eA1.x, W[0][1], fmaf(eA1.y, W[1][1], fmaf(eA1.z, W[2][1], bb[1])));
        float ud2 = fmaf(eA1.x, W[0][2], fmaf(eA1.y, W[1][2], fmaf(eA1.z, W[2][2], bb[2])));
        acc1 += fmaf(x10, ud0, fmaf(x11, ud1, x12 * ud2));
    }
    if (j < j1) {
        float4 eA0 = edataA[j];
        int s0 = __float_as_int(eA0.w);
        float x00 = x[s0*3], x01 = x[s0*3+1], x02 = x[s0*3+2];
        float wd0 = fmaf(eA0.x, W[0][0], fmaf(eA0.y, W[1][0], fmaf(eA0.z, W[2][0], bb[0])));
        float wd1 = fmaf(eA0.x, W[0][1], fmaf(eA0.y, W[1][1], fmaf(eA0.z, W[2][1], bb[1])));
        float wd2 = fmaf(eA0.x, W[0][2], fmaf(eA0.y, W[1][2], fmaf(eA0.z, W[2][2], bb[2])));
        acc0 += fmaf(x00, wd0, fmaf(x01, wd1, x02 * wd2));
    }
    float v = acc0 + acc1 + b1[o];
    v = fmaf(x[n*3],   root1[o],      v);
    v = fmaf(x[n*3+1], root1[32 + o], v);
    v = fmaf(x[n*3+2], root1[64 + o], v);
    h1[(size_t)n*32 + o] = fmaxf(v, 0.f);
}

// ---------- prep2: wave-per-node; h0 lanes {g0,g1}, h1 lanes {g2,g3,r2} ----------
__global__ __launch_bounds__(256) void prep2_kernel(const float* __restrict__ h1,
                                                    const float* __restrict__ Wn2,
                                                    const float* __restrict__ bn2,
                                                    const float* __restrict__ root2,
                                                    unsigned int* __restrict__ G2u,
                                                    __half* __restrict__ R2h) {
    int lane = threadIdx.x & 63;
    int h = lane >> 5, o = lane & 31;
    const float* q0 = (h == 0) ? (Wn2)        : (Wn2 + 2048);  // g0 | g2
    const float* q1 = (h == 0) ? (Wn2 + 1024) : (bn2);         // g1 | g3
    float w0[32], w1[32], w2[32];
    #pragma unroll
    for (int i = 0; i < 32; ++i) {
        w0[i] = q0[i*32 + o];
        w1[i] = q1[i*32 + o];
        w2[i] = root2[i*32 + o];          // consumed by h==1 only
    }
    int w = (blockIdx.x * 256 + threadIdx.x) >> 6;
    int nwaves = (gridDim.x * 256) >> 6;
    for (int n = w; n < N_NODES; n += nwaves) {
        int nu = __builtin_amdgcn_readfirstlane(n);
        const float4* hv = (const float4*)(h1 + (size_t)nu * 32);
        float a0 = 0.f, a1 = 0.f, a2 = 0.f;
        #pragma unroll
        for (int i4 = 0; i4 < 8; ++i4) {
            float4 t = hv[i4];                          // wave-uniform -> s_load
            a0 = fmaf(t.x, w0[i4*4+0], a0); a1 = fmaf(t.x, w1[i4*4+0], a1); a2 = fmaf(t.x, w2[i4*4+0], a2);
            a0 = fmaf(t.y, w0[i4*4+1], a0); a1 = fmaf(t.y, w1[i4*4+1], a1); a2 = fmaf(t.y, w2[i4*4+1], a2);
            a0 = fmaf(t.z, w0[i4*4+2], a0); a1 = fmaf(t.z, w1[i4*4+2], a1); a2 = fmaf(t.z, w2[i4*4+2], a2);
            a0 = fmaf(t.w, w0[i4*4+3], a0); a1 = fmaf(t.w, w1[i4*4+3], a1); a2 = fmaf(t.w, w2[i4*4+3], a2);
        }
        __half2 p = __floats2half2_rn(a0, a1);
        G2u[(size_t)nu*64 + o*2 + h] = *(const unsigned int*)&p;
        if (h) R2h[(size_t)nu*32 + o] = __float2half(a2);
    }
}

// ---------- conv2: gather + R2h + b2 + ReLU -> final h2 ----------
__global__ __launch_bounds__(256) void conv2_kernel(const int* __restrict__ rowptr,
                                                    const float4* __restrict__ edataA,
                                                    const uint2* __restrict__ G2h,
                                                    const __half* __restrict__ R2h,
                                                    const float* __restrict__ b2,
                                                    float* __restrict__ h2out) {
    int gid = blockIdx.x * 256 + threadIdx.x;
    int n = gid >> 5, o = gid & 31;
    if (n >= N_NODES) return;
    int j0 = rowptr[n], j1 = rowptr[n + 1];
    float a0 = 0.f, a1 = 0.f;
    int j = j0;
    for (; j + 2 <= j1; j += 2) {
        float4 e0 = edataA[j], e1 = edataA[j+1];
        uint2 p0 = G2h[(size_t)__float_as_int(e0.w)*32 + o];
        uint2 p1 = G2h[(size_t)__float_as_int(e1.w)*32 + o];
        float2 f0a = __half22float2(*(const __half2*)&p0.x);
        float2 f0b = __half22float2(*(const __half2*)&p0.y);
        float2 f1a = __half22float2(*(const __half2*)&p1.x);
        float2 f1b = __half22float2(*(const __half2*)&p1.y);
        a0 += fmaf(e0.x, f0a.x, fmaf(e0.y, f0a.y, fmaf(e0.z, f0b.x, f0b.y)));
        a1 += fmaf(e1.x, f1a.x, fmaf(e1.y, f1a.y, fmaf(e1.z, f1b.x, f1b.y)));
    }
    if (j < j1) {
        float4 e0 = edataA[j];
        uint2 p0 = G2h[(size_t)__float_as_int(e0.w)*32 + o];
        float2 f0a = __half22float2(*(const __half2*)&p0.x);
        float2 f0b = __half22float2(*(const __half2*)&p0.y);
        a0 += fmaf(e0.x, f0a.x, fmaf(e0.y, f0a.y, fmaf(e0.z, f0b.x, f0b.y)));
    }
    float v = a0 + a1 + __half2float(R2h[(size_t)n*32 + o]) + b2[o];
    h2out[(size_t)n*32 + o] = fmaxf(v, 0.f);
}

// ---------- node2: pure FC1 + FC2, node-per-thread (uniform weights) ----------
__global__ __launch_bounds__(256) void node2_kernel(const float* __restrict__ h2,
                                                    const float* __restrict__ Wf1,
                                                    const float* __restrict__ bf1,
                                                    const float* __restrict__ Wf2,
                                                    const float* __restrict__ bf2,
                                                    float* __restrict__ out) {
    int n = blockIdx.x * 256 + threadIdx.x;
    if (n >= N_NODES) return;
    float hr[32];
    const float4* hv = (const float4*)(h2 + (size_t)n * 32);
    #pragma unroll
    for (int j4 = 0; j4 < 8; ++j4) {
        float4 t = hv[j4];
        hr[j4*4+0] = t.x; hr[j4*4+1] = t.y; hr[j4*4+2] = t.z; hr[j4*4+3] = t.w;
    }
    float acc2 = bf2[0];
    #pragma unroll
    for (int j = 0; j < 32; ++j) {
        float a = bf1[j];
        #pragma unroll
        for (int i = 0; i < 32; ++i) a = fmaf(hr[i], Wf1[i*32 + j], a);
        acc2 = fmaf(fmaxf(a, 0.f), Wf2[j], acc2);
    }
    out[n] = acc2;
}

extern "C" void kernel_launch(void* const* d_in, const int* in_sizes, int n_in,
                              void* d_out, int out_size, void* d_ws, size_t ws_size,
                              hipStream_t stream) {
    const float* x     = (const float*)d_in[0];
    const int*   ei    = (const int*)  d_in[1];
    const float* ea    = (const float*)d_in[2];
    const float* Wn1   = (const float*)d_in[3];
    const float* bn1   = (const float*)d_in[4];
    const float* root1 = (const float*)d_in[5];
    const float* b1    = (const float*)d_in[6];
    const float* Wn2   = (const float*)d_in[7];
    const float* bn2   = (const float*)d_in[8];
    const float* root2 = (const float*)d_in[9];
    const float* b2    = (const float*)d_in[10];
    const float* Wf1   = (const float*)d_in[11];
    const float* bf1   = (const float*)d_in[12];
    const float* Wf2   = (const float*)d_in[13];
    const float* bf2   = (const float*)d_in[14];
    float* out = (float*)d_out;

    // workspace carve
    float*  h1     = (float*)d_ws;                          // [N,32] f32
    float*  h2     = h1 + (size_t)N_NODES*32;               // [N,32] f32
    unsigned int* G2u = (unsigned int*)(h2 + (size_t)N_NODES*32); // [N,64] u32 (fp16x2)
    __half* R2h    = (__half*)(G2u + (size_t)N_NODES*64);   // [N,32] fp16
    float4* edataA = (float4*)(R2h + (size_t)N_NODES*32);   // [E]
    int*    deg    = (int*)(edataA + N_EDGES);              // [N]
    int*    rowptr = deg + N_NODES;                         // [N+1]
    int*    rank   = rowptr + N_NODES + 1;                  // [E]
    int*    psum   = rank + N_EDGES;                        // [SCAN_BLOCKS]

    int eb   = (N_EDGES + 255) / 256;                       // 1563
    int nb   = (N_NODES + 255) / 256;                       // 391
    int nb32 = (N_NODES * 32 + 255) / 256;                  // 12500
    int zb   = (N_NODES / 4 + 255) / 256;                   // 98

    zero_kernel   <<<zb, 256, 0, stream>>>((int4*)deg);
    hist_kernel   <<<eb, 256, 0, stream>>>(ei, deg, rank);
    scanA_kernel  <<<SCAN_BLOCKS, 256, 0, stream>>>(deg, rowptr, psum);
    scanBC_kernel <<<SCAN_BLOCKS, 256, 0, stream>>>(psum, rowptr);
    scatter_kernel<<<eb, 256, 0, stream>>>(ei, ea, rowptr, rank, edataA);
    conv1_kernel  <<<nb32, 256, 0, stream>>>(rowptr, edataA, x, Wn1, bn1, root1, b1, h1);
    prep2_kernel  <<<1536, 256, 0, stream>>>(h1, Wn2, bn2, root2, G2u, R2h);
    conv2_kernel  <<<nb32, 256, 0, stream>>>(rowptr, edataA, (const uint2*)G2u, R2h, b2, h2);
    node2_kernel  <<<nb, 256, 0, stream>>>(h2, Wf1, bf1, Wf2, bf2, out);
}